// Round 5
// baseline (141.991 us; speedup 1.0000x reference)
//
#include <hip/hip_runtime.h>
#include <math.h>

// Problem: B=2, L=2048, H=16, E=64. fp32 in/out.
#define LL 2048
#define HH 16
#define EE 64
#define ROWSTR (HH*EE)          // float stride between consecutive seq rows (same h)
#define NBH 32                  // B*H
#define NT 16                   // 128-row q tiles per (b,h)
#define SCALE 0.125f
#define LOG2E 1.4426950408889634f
#define OSZ (2*LL*HH*EE)        // floats per partial-O copy (4,194,304)
#define NL  (2*LL*HH)           // l entries per split (65,536)
#define WS_NEED ((size_t)(2*OSZ + 2*NL) * 4)

using bf16x8 = __attribute__((ext_vector_type(8))) __bf16;
using f32x4  = __attribute__((ext_vector_type(4))) float;
using s16x4  = __attribute__((ext_vector_type(4))) short;

// fast fp32->bf16 (round-half-up) pair pack: 2 adds + 1 v_perm
__device__ __forceinline__ unsigned pkbf(float lo, float hi) {
    unsigned l = __builtin_bit_cast(unsigned, lo) + 0x8000u;
    unsigned h = __builtin_bit_cast(unsigned, hi) + 0x8000u;
    return __builtin_amdgcn_perm(h, l, 0x07060302u);
}
__device__ __forceinline__ uint4 pack8(float4 a, float4 b) {
    uint4 u; u.x = pkbf(a.x, a.y); u.y = pkbf(a.z, a.w);
    u.z = pkbf(b.x, b.y); u.w = pkbf(b.z, b.w); return u;
}

// K=16 bf16 MFMA: B-frag layout B[k=quad*4+j][col=m] matches QK C-layout exactly.
#if __has_builtin(__builtin_amdgcn_mfma_f32_16x16x16_bf16)
using bf16x4 = __attribute__((ext_vector_type(4))) __bf16;
__device__ __forceinline__ f32x4 mfma16(s16x4 a, s16x4 b, f32x4 c) {
    return __builtin_amdgcn_mfma_f32_16x16x16_bf16(
        __builtin_bit_cast(bf16x4, a), __builtin_bit_cast(bf16x4, b), c, 0, 0, 0);
}
#else
__device__ __forceinline__ f32x4 mfma16(s16x4 a, s16x4 b, f32x4 c) {
    return __builtin_amdgcn_mfma_f32_16x16x16bf16_1k(a, b, c, 0, 0, 0);
}
#endif

// WG = 512 thr = 8 waves; one (b,h,128-row q tile[, key-split half]).
// Fixed-reference softmax: p = exp2(S) directly (logits bounded), so partial
// (unnormalized O, l) over disjoint key ranges are additive -> 2-way key split.
template<int SPLITMODE>
__global__ __launch_bounds__(512, 4) void dsattn(
    const float* __restrict__ Qg, const float* __restrict__ Kg,
    const float* __restrict__ Vg, const float* __restrict__ taug,
    const float* __restrict__ dg, float* __restrict__ Og,
    float* __restrict__ ws)
{
    __shared__ __align__(16) unsigned short Ks[2][64 * 64];
    __shared__ __align__(16) unsigned short Vt[2][64 * 64];

    const int tid  = threadIdx.x;
    const int w    = tid >> 6;       // wave 0..7
    const int lane = tid & 63;
    const int m    = lane & 15;
    const int quad = lane >> 4;

    const int bid = blockIdx.x;
    int tt, bh, split;
    if (SPLITMODE) {
        tt = (NT - 1) - (bid >> 6);          // longest first
        bh = bid & 31;
        split = (bid >> 5) & 1;
    } else {
        const int g = bid >> 5;
        tt = (g < 8) ? (15 - g) : (g - 8);
        bh = bid & 31;
        split = 0;
    }
    const int b = bh >> 4;
    const int h = bh & 15;
    const int s_begin = (SPLITMODE && split) ? (tt + 1) : 0;
    const int s_end   = (SPLITMODE && !split) ? (tt + 1) : (2 * tt + 2);

    const float qscale = taug[b] * (SCALE * LOG2E);
    const float dscale = SCALE * LOG2E;
    const int diag_st = 2 * tt + (w >> 2);          // last key tile this wave needs
    const int thr = (w & 3) * 16 + m - quad * 4;    // mask when 16n + r > thr at diag

    // ---- Q fragment (B-operand: B[k=e][col=q=lane&15]) with tau*scale*log2e folded ----
    bf16x8 qb[2];
    {
        const float* qp = Qg + ((size_t)(b * LL + tt * 128 + w * 16 + m) * HH + h) * EE + quad * 8;
        #pragma unroll
        for (int ch = 0; ch < 2; ++ch) {
            float4 f0 = *(const float4*)(qp + ch * 32);
            float4 f1 = *(const float4*)(qp + ch * 32 + 4);
            f0.x *= qscale; f0.y *= qscale; f0.z *= qscale; f0.w *= qscale;
            f1.x *= qscale; f1.y *= qscale; f1.z *= qscale; f1.w *= qscale;
            qb[ch] = __builtin_bit_cast(bf16x8, pack8(f0, f1));
        }
    }

    // staging index precompute (512 threads)
    const int skey = tid >> 3, kc = tid & 7, se0 = (tid & 7) * 8;
    const int sv = (tid & 31) * 2, ve = (tid >> 5) * 4;
    const float* kbase = Kg + ((size_t)b * LL * HH + h) * EE;
    const float* vbase = Vg + ((size_t)b * LL * HH + h) * EE;
    const float* dbase = dg + b * LL;

    // prologue prefetch (tile s_begin)
    float4 kr0, kr1, va, vb, dr0, dr1, dr2, dr3;
    {
        const int row = s_begin * 64;
        const float* kp = kbase + (size_t)(row + skey) * ROWSTR + se0;
        kr0 = ((const float4*)kp)[0]; kr1 = ((const float4*)kp)[1];
        const float* vp = vbase + (size_t)(row + sv) * ROWSTR + ve;
        va = *(const float4*)(vp); vb = *(const float4*)(vp + ROWSTR);
        const float* dp = dbase + row + quad * 4;
        dr0 = *(const float4*)(dp); dr1 = *(const float4*)(dp + 16);
        dr2 = *(const float4*)(dp + 32); dr3 = *(const float4*)(dp + 48);
    }

    f32x4 Oacc[4] = {};
    float l_ = 0.f;

    for (int st = s_begin; st < s_end; ++st) {
        const int par = st & 1;
        unsigned short* KsP = Ks[par];
        unsigned short* VtP = Vt[par];

        // ---- LDS staging from prefetched regs ----
        *(uint4*)&KsP[skey * 64 + (kc ^ (skey & 7)) * 8] = pack8(kr0, kr1);
        {
            float ra[4] = {va.x, va.y, va.z, va.w};
            float rb[4] = {vb.x, vb.y, vb.z, vb.w};
            #pragma unroll
            for (int i = 0; i < 4; ++i) {
                const int e = ve + i;
                *(unsigned*)&VtP[e * 64 + (((sv >> 3) ^ (e & 7)) * 8) + (sv & 7)] = pkbf(ra[i], rb[i]);
            }
        }
        __syncthreads();

        // this tile's delta (fp32-exact C-init, scale*log2e folded)
        f32x4 dvx[4];
        dvx[0] = f32x4{dr0.x * dscale, dr0.y * dscale, dr0.z * dscale, dr0.w * dscale};
        dvx[1] = f32x4{dr1.x * dscale, dr1.y * dscale, dr1.z * dscale, dr1.w * dscale};
        dvx[2] = f32x4{dr2.x * dscale, dr2.y * dscale, dr2.z * dscale, dr2.w * dscale};
        dvx[3] = f32x4{dr3.x * dscale, dr3.y * dscale, dr3.z * dscale, dr3.w * dscale};

        // ---- prefetch next tile into regs (overlaps with compute below) ----
        if (st + 1 < s_end) {
            const int row = (st + 1) * 64;
            const float* kp = kbase + (size_t)(row + skey) * ROWSTR + se0;
            kr0 = ((const float4*)kp)[0]; kr1 = ((const float4*)kp)[1];
            const float* vp = vbase + (size_t)(row + sv) * ROWSTR + ve;
            va = *(const float4*)(vp); vb = *(const float4*)(vp + ROWSTR);
            const float* dp = dbase + row + quad * 4;
            dr0 = *(const float4*)(dp); dr1 = *(const float4*)(dp + 16);
            dr2 = *(const float4*)(dp + 32); dr3 = *(const float4*)(dp + 48);
        }

        if (st <= diag_st) {
            // ---- S^T = K·Q^T + delta  (D rows=keys, cols=q), log2 units ----
            f32x4 S[4];
            #pragma unroll
            for (int n = 0; n < 4; ++n) {
                bf16x8 kf = *(const bf16x8*)&KsP[(16 * n + m) * 64 + (quad ^ (m & 7)) * 8];
                S[n] = __builtin_amdgcn_mfma_f32_16x16x32_bf16(kf, qb[0], dvx[n], 0, 0, 0);
            }
            #pragma unroll
            for (int n = 0; n < 4; ++n) {
                bf16x8 kf = *(const bf16x8*)&KsP[(16 * n + m) * 64 + ((quad + 4) ^ (m & 7)) * 8];
                S[n] = __builtin_amdgcn_mfma_f32_16x16x32_bf16(kf, qb[1], S[n], 0, 0, 0);
            }

            // causal mask on the diagonal tile only
            if (st == diag_st) {
                #pragma unroll
                for (int n = 0; n < 4; ++n)
                    #pragma unroll
                    for (int r = 0; r < 4; ++r)
                        if (16 * n + r > thr) S[n][r] = -INFINITY;
            }

            // ---- fixed-ref softmax: p = exp2(S); accumulate l per lane ----
            float rs[4];
            #pragma unroll
            for (int n = 0; n < 4; ++n) {
                float p0 = __builtin_amdgcn_exp2f(S[n][0]);
                float p1 = __builtin_amdgcn_exp2f(S[n][1]);
                float p2 = __builtin_amdgcn_exp2f(S[n][2]);
                float p3 = __builtin_amdgcn_exp2f(S[n][3]);
                S[n][0] = p0; S[n][1] = p1; S[n][2] = p2; S[n][3] = p3;
                rs[n] = (p0 + p1) + (p2 + p3);
            }
            l_ += (rs[0] + rs[1]) + (rs[2] + rs[3]);

            // ---- pack P as K=16 B-frags (register-direct, no LDS round trip) ----
            s16x4 pb[4];
            #pragma unroll
            for (int n = 0; n < 4; ++n) {
                uint2 u; u.x = pkbf(S[n][0], S[n][1]); u.y = pkbf(S[n][2], S[n][3]);
                pb[n] = __builtin_bit_cast(s16x4, u);
            }

            // ---- O^T += V^T · P^T via 16x16x16 MFMAs ----
            #pragma unroll
            for (int eb = 0; eb < 4; ++eb) {
                const int e = 16 * eb + m;
                s16x4 vf[4];
                #pragma unroll
                for (int n = 0; n < 4; ++n)
                    vf[n] = *(const s16x4*)&VtP[e * 64 + (((2 * n + (quad >> 1)) ^ (m & 7)) * 8) + (quad & 1) * 4];
                #pragma unroll
                for (int n = 0; n < 4; ++n)
                    Oacc[eb] = mfma16(vf[n], pb[n], Oacc[eb]);
            }
        }
    }

    // ---- epilogue ----
    {
        float lt = l_ + __shfl_xor(l_, 16);
        lt = lt + __shfl_xor(lt, 32);
        const int q = tt * 128 + w * 16 + m;
        if (SPLITMODE) {
            // write unnormalized partial O + l to workspace
            float* Opw = ws + (size_t)split * OSZ
                       + ((size_t)(b * LL + q) * HH + h) * EE + quad * 4;
            #pragma unroll
            for (int n = 0; n < 4; ++n) {
                float4 o = {Oacc[n][0], Oacc[n][1], Oacc[n][2], Oacc[n][3]};
                *(float4*)(Opw + 16 * n) = o;
            }
            if (quad == 0)
                ws[(size_t)2 * OSZ + (size_t)split * NL + (size_t)(b * LL + q) * HH + h] = lt;
        } else {
            const float inv = __builtin_amdgcn_rcpf(lt);
            float* op = Og + ((size_t)(b * LL + q) * HH + h) * EE + quad * 4;
            #pragma unroll
            for (int n = 0; n < 4; ++n) {
                float4 o = {Oacc[n][0] * inv, Oacc[n][1] * inv, Oacc[n][2] * inv, Oacc[n][3] * inv};
                *(float4*)(op + 16 * n) = o;
            }
        }
    }
}

// combine: out = (O0 + O1) / (l0 + l1); one float4 per thread.
__global__ __launch_bounds__(256) void dscombine(
    const float* __restrict__ ws, float* __restrict__ out)
{
    const int gid = blockIdx.x * 256 + threadIdx.x;   // float4 index
    const float4* O0 = (const float4*)ws;
    const float4* O1 = (const float4*)(ws + OSZ);
    const float* l0 = ws + (size_t)2 * OSZ;
    const float* l1 = l0 + NL;
    const int j = gid >> 4;                           // (b,q,h) row index
    const float inv = __builtin_amdgcn_rcpf(l0[j] + l1[j]);
    float4 a = O0[gid], c = O1[gid];
    float4 o = {(a.x + c.x) * inv, (a.y + c.y) * inv,
                (a.z + c.z) * inv, (a.w + c.w) * inv};
    ((float4*)out)[gid] = o;
}

extern "C" void kernel_launch(void* const* d_in, const int* in_sizes, int n_in,
                              void* d_out, int out_size, void* d_ws, size_t ws_size,
                              hipStream_t stream) {
    const float* Q     = (const float*)d_in[0];
    const float* K     = (const float*)d_in[1];
    const float* V     = (const float*)d_in[2];
    const float* tau   = (const float*)d_in[3];
    const float* delta = (const float*)d_in[4];
    float* out = (float*)d_out;
    float* ws  = (float*)d_ws;
    if (ws_size >= WS_NEED) {
        dsattn<1><<<dim3(2 * NBH * NT), dim3(512), 0, stream>>>(Q, K, V, tau, delta, out, ws);
        dscombine<<<dim3(OSZ / 4 / 256), dim3(256), 0, stream>>>(ws, out);
    } else {
        dsattn<0><<<dim3(NBH * NT), dim3(512), 0, stream>>>(Q, K, V, tau, delta, out, ws);
    }
}

// Round 6
// 135.420 us; speedup vs baseline: 1.0485x; 1.0485x over previous
//
#include <hip/hip_runtime.h>
#include <math.h>

// Problem: B=2, L=2048, H=16, E=64. fp32 in/out.
#define LL 2048
#define HH 16
#define EE 64
#define ROWSTR (HH*EE)
#define NBH 32                  // B*H
#define NT 16                   // 128-row q tiles per (b,h)
#define NST 32                  // 64-key tiles per (b,h)
#define SCALE 0.125f
#define LOG2E 1.4426950408889634f
#define TILE_SH 4096            // shorts per 64x64 bf16 tile image
// ws layout: [4096 floats dscaled][Kpre bf16 images][Vpre bf16 images]
#define KPRE_OFF 4096                                   // in floats
#define TILES_TOTAL ((size_t)NBH * NST)
#define WS_NEED (16384ull + 2ull * TILES_TOTAL * TILE_SH * 2ull)

using bf16x8 = __attribute__((ext_vector_type(8))) __bf16;
using f32x4  = __attribute__((ext_vector_type(4))) float;
using s16x4  = __attribute__((ext_vector_type(4))) short;

// fast fp32->bf16 (round-half-up) pair pack: 2 adds + 1 v_perm
__device__ __forceinline__ unsigned pkbf(float lo, float hi) {
    unsigned l = __builtin_bit_cast(unsigned, lo) + 0x8000u;
    unsigned h = __builtin_bit_cast(unsigned, hi) + 0x8000u;
    return __builtin_amdgcn_perm(h, l, 0x07060302u);
}
__device__ __forceinline__ uint4 pack8(float4 a, float4 b) {
    uint4 u; u.x = pkbf(a.x, a.y); u.y = pkbf(a.z, a.w);
    u.z = pkbf(b.x, b.y); u.w = pkbf(b.z, b.w); return u;
}

#if __has_builtin(__builtin_amdgcn_mfma_f32_16x16x16_bf16)
using bf16x4 = __attribute__((ext_vector_type(4))) __bf16;
__device__ __forceinline__ f32x4 mfma16(s16x4 a, s16x4 b, f32x4 c) {
    return __builtin_amdgcn_mfma_f32_16x16x16_bf16(
        __builtin_bit_cast(bf16x4, a), __builtin_bit_cast(bf16x4, b), c, 0, 0, 0);
}
#else
__device__ __forceinline__ f32x4 mfma16(s16x4 a, s16x4 b, f32x4 c) {
    return __builtin_amdgcn_mfma_f32_16x16x16bf16_1k(a, b, c, 0, 0, 0);
}
#endif

// async 16B global->LDS (CK-style address-space casts)
__device__ __forceinline__ void gl_lds16(const void* g, void* l) {
    __builtin_amdgcn_global_load_lds(
        (const __attribute__((address_space(1))) unsigned int*)(unsigned long long)g,
        (__attribute__((address_space(3))) unsigned int*)(unsigned long long)l,
        16, 0, 0);
}

// ---------------- prep: K/V -> bf16 DMA-ready tile images + delta prescale ----
// K image: row k (natural), 8 chunks of 8 shorts, chunk c at position c^(k&7).
// V image: row e, column sigma(s) = (s&3) + ((s>>4)&3)*4 + ((s>>2)&3)*16,
//          chunk c at position c^(e&7).  (sigma makes PV A-frags contiguous b128)
__global__ __launch_bounds__(256) void dsprep(
    const float* __restrict__ K, const float* __restrict__ V,
    const float* __restrict__ delta, float* __restrict__ ws)
{
    const int bid = blockIdx.x;
    const int t = threadIdx.x;
    float* dsc = ws;
    unsigned short* kpre = (unsigned short*)(ws + KPRE_OFF);
    unsigned short* vpre = kpre + TILES_TOTAL * TILE_SH;

    if (bid >= NBH * NST) {               // delta prescale: 16 trailing blocks
        const int i = (bid - NBH * NST) * 256 + t;
        dsc[i] = delta[i] * (SCALE * LOG2E);
        return;
    }
    const int bh = bid & 31, st = bid >> 5;
    const int b = bh >> 4, h = bh & 15;

    // ---- K tile ----
    unsigned short* kimg = kpre + ((size_t)bh * NST + st) * TILE_SH;
    #pragma unroll
    for (int i = 0; i < 2; ++i) {
        const int slot = t + i * 256;     // 0..511: (k, chunk)
        const int k = slot >> 3, c = slot & 7;
        const float* src = K + ((size_t)(b * LL + st * 64 + k) * HH + h) * EE + c * 8;
        float4 a = ((const float4*)src)[0], bq = ((const float4*)src)[1];
        *(uint4*)&kimg[k * 64 + (c ^ (k & 7)) * 8] = pack8(a, bq);
    }

    // ---- V tile: coalesced read -> LDS fp32 (padded) -> transposed bf16 image ----
    __shared__ float vt[64 * 65];
    {
        const int s = t >> 2, seg = (t & 3) * 16;
        const float* src = V + ((size_t)(b * LL + st * 64 + s) * HH + h) * EE + seg;
        #pragma unroll
        for (int i = 0; i < 4; ++i) {
            float4 f = ((const float4*)src)[i];
            vt[s * 65 + seg + 4 * i + 0] = f.x;
            vt[s * 65 + seg + 4 * i + 1] = f.y;
            vt[s * 65 + seg + 4 * i + 2] = f.z;
            vt[s * 65 + seg + 4 * i + 3] = f.w;
        }
    }
    __syncthreads();
    {
        unsigned short* vimg = vpre + ((size_t)bh * NST + st) * TILE_SH;
        const int e = t >> 2, g = t & 3;  // sigma range [16g, 16g+16)
        unsigned u[8];
        #pragma unroll
        for (int A = 0; A < 4; ++A) {     // sigma = 16g + 4A + C  <->  s = 16A + 4g + C
            float x0 = vt[(16 * A + 4 * g + 0) * 65 + e];
            float x1 = vt[(16 * A + 4 * g + 1) * 65 + e];
            float x2 = vt[(16 * A + 4 * g + 2) * 65 + e];
            float x3 = vt[(16 * A + 4 * g + 3) * 65 + e];
            u[2 * A]     = pkbf(x0, x1);
            u[2 * A + 1] = pkbf(x2, x3);
        }
        *(uint4*)&vimg[e * 64 + ((2 * g)     ^ (e & 7)) * 8] = uint4{u[0], u[1], u[2], u[3]};
        *(uint4*)&vimg[e * 64 + ((2 * g + 1) ^ (e & 7)) * 8] = uint4{u[4], u[5], u[6], u[7]};
    }
}

// ---------------- main: DMA-staged flash attention ----------------
// WG = 512 thr = 8 waves; one (b,h,128-row q tile). Fixed-reference softmax
// (p = exp2(S), logits bounded). K/V tiles arrive via global_load_lds (async,
// zero staging VALU), double-buffered, one barrier per key tile.
__global__ __launch_bounds__(512, 4) void dsattn_dma(
    const float* __restrict__ Qg, const float* __restrict__ taug,
    const float* __restrict__ ws_, float* __restrict__ Og)
{
    __shared__ __align__(16) unsigned short Ks[2][TILE_SH];
    __shared__ __align__(16) unsigned short Vt[2][TILE_SH];

    const int tid  = threadIdx.x;
    const int w    = tid >> 6;
    const int lane = tid & 63;
    const int m    = lane & 15;
    const int quad = lane >> 4;

    const int bid = blockIdx.x;
    const int bh  = bid & (NBH - 1);
    const int g   = bid >> 5;
    const int tt  = (g < 8) ? (15 - g) : (g - 8);   // pair big+small per CU
    const int b   = bh >> 4;
    const int h   = bh & 15;

    const float* dsc = ws_;
    const unsigned short* kpre = (const unsigned short*)(ws_ + KPRE_OFF);
    const unsigned short* vpre = kpre + TILES_TOTAL * TILE_SH;
    const unsigned short* ktiles = kpre + (size_t)bh * NST * TILE_SH;
    const unsigned short* vtiles = vpre + (size_t)bh * NST * TILE_SH;

    const float qscale = taug[b] * (SCALE * LOG2E);
    const int diag_st = 2 * tt + (w >> 2);
    const int thr = (w & 3) * 16 + m - quad * 4;    // mask when 16n + r > thr at diag

    // ---- Q fragment (B-operand: B[k=e][col=q=m]) with tau*scale*log2e folded ----
    bf16x8 qb[2];
    {
        const float* qp = Qg + ((size_t)(b * LL + tt * 128 + w * 16 + m) * HH + h) * EE + quad * 8;
        #pragma unroll
        for (int ch = 0; ch < 2; ++ch) {
            float4 f0 = *(const float4*)(qp + ch * 32);
            float4 f1 = *(const float4*)(qp + ch * 32 + 4);
            f0.x *= qscale; f0.y *= qscale; f0.z *= qscale; f0.w *= qscale;
            f1.x *= qscale; f1.y *= qscale; f1.z *= qscale; f1.w *= qscale;
            qb[ch] = __builtin_bit_cast(bf16x8, pack8(f0, f1));
        }
    }

    const int nst = 2 * tt + 2;
    const float* dbase = dsc + b * LL + quad * 4;

    // prologue DMA: tile 0 -> buffer 0 (each thread moves 16B of K and 16B of V)
    gl_lds16(ktiles + tid * 8, &Ks[0][w * 512]);
    gl_lds16(vtiles + tid * 8, &Vt[0][w * 512]);

    f32x4 Oacc[4] = {};
    float l_ = 0.f;

    for (int st = 0; st < nst; ++st) {
        const int par = st & 1;
        const unsigned short* KsP = Ks[par];
        const unsigned short* VtP = Vt[par];

        __syncthreads();   // drains this tile's DMA + prior reads of the other buffer

        // async prefetch next tile into the other buffer (overlaps compute)
        if (st + 1 < nst) {
            gl_lds16(ktiles + (st + 1) * TILE_SH + tid * 8, &Ks[par ^ 1][w * 512]);
            gl_lds16(vtiles + (st + 1) * TILE_SH + tid * 8, &Vt[par ^ 1][w * 512]);
        }

        if (st <= diag_st) {
            // delta for this tile (prescaled, fp32-exact C-init)
            const float* dp = dbase + st * 64;
            float4 dr0 = *(const float4*)(dp);
            float4 dr1 = *(const float4*)(dp + 16);
            float4 dr2 = *(const float4*)(dp + 32);
            float4 dr3 = *(const float4*)(dp + 48);

            // ---- S^T = K·Q^T + delta  (D rows=keys, cols=q), log2 units ----
            f32x4 S[4];
            S[0] = __builtin_bit_cast(f32x4, dr0);
            S[1] = __builtin_bit_cast(f32x4, dr1);
            S[2] = __builtin_bit_cast(f32x4, dr2);
            S[3] = __builtin_bit_cast(f32x4, dr3);
            #pragma unroll
            for (int n = 0; n < 4; ++n) {
                bf16x8 kf = *(const bf16x8*)&KsP[(16 * n + m) * 64 + (quad ^ (m & 7)) * 8];
                S[n] = __builtin_amdgcn_mfma_f32_16x16x32_bf16(kf, qb[0], S[n], 0, 0, 0);
            }
            #pragma unroll
            for (int n = 0; n < 4; ++n) {
                bf16x8 kf = *(const bf16x8*)&KsP[(16 * n + m) * 64 + ((quad + 4) ^ (m & 7)) * 8];
                S[n] = __builtin_amdgcn_mfma_f32_16x16x32_bf16(kf, qb[1], S[n], 0, 0, 0);
            }

            if (st == diag_st) {   // causal mask, diagonal tile only
                #pragma unroll
                for (int n = 0; n < 4; ++n)
                    #pragma unroll
                    for (int r = 0; r < 4; ++r)
                        if (16 * n + r > thr) S[n][r] = -INFINITY;
            }

            // ---- fixed-ref softmax: p = exp2(S) ----
            float rs[4];
            #pragma unroll
            for (int n = 0; n < 4; ++n) {
                float p0 = __builtin_amdgcn_exp2f(S[n][0]);
                float p1 = __builtin_amdgcn_exp2f(S[n][1]);
                float p2 = __builtin_amdgcn_exp2f(S[n][2]);
                float p3 = __builtin_amdgcn_exp2f(S[n][3]);
                S[n][0] = p0; S[n][1] = p1; S[n][2] = p2; S[n][3] = p3;
                rs[n] = (p0 + p1) + (p2 + p3);
            }
            l_ += (rs[0] + rs[1]) + (rs[2] + rs[3]);

            // ---- pack P as K=16 B-frags (register-direct) ----
            s16x4 pb[4];
            #pragma unroll
            for (int n = 0; n < 4; ++n) {
                uint2 u; u.x = pkbf(S[n][0], S[n][1]); u.y = pkbf(S[n][2], S[n][3]);
                pb[n] = __builtin_bit_cast(s16x4, u);
            }

            // ---- O^T += V^T·P^T; sigma layout -> 2 contiguous b128 per eb ----
            #pragma unroll
            for (int eb = 0; eb < 4; ++eb) {
                const int e = 16 * eb + m;
                uint4 r0 = *(const uint4*)&VtP[e * 64 + ((2 * quad)     ^ (m & 7)) * 8];
                uint4 r1 = *(const uint4*)&VtP[e * 64 + ((2 * quad + 1) ^ (m & 7)) * 8];
                f32x4 o = Oacc[eb];
                o = mfma16(__builtin_bit_cast(s16x4, uint2{r0.x, r0.y}), pb[0], o);
                o = mfma16(__builtin_bit_cast(s16x4, uint2{r0.z, r0.w}), pb[1], o);
                o = mfma16(__builtin_bit_cast(s16x4, uint2{r1.x, r1.y}), pb[2], o);
                o = mfma16(__builtin_bit_cast(s16x4, uint2{r1.z, r1.w}), pb[3], o);
                Oacc[eb] = o;
            }
        }
    }

    // ---- epilogue: reduce l across quads, normalize, float4 stores ----
    {
        float lt = l_ + __shfl_xor(l_, 16);
        lt = lt + __shfl_xor(lt, 32);
        const float inv = __builtin_amdgcn_rcpf(lt);
        float* op = Og + ((size_t)(b * LL + tt * 128 + w * 16 + m) * HH + h) * EE + quad * 4;
        #pragma unroll
        for (int n = 0; n < 4; ++n) {
            float4 o = {Oacc[n][0] * inv, Oacc[n][1] * inv, Oacc[n][2] * inv, Oacc[n][3] * inv};
            *(float4*)(op + 16 * n) = o;
        }
    }
}

// ---------------- fallback (R4 register-staging path, no workspace) ----------
__global__ __launch_bounds__(512, 4) void dsattn_reg(
    const float* __restrict__ Qg, const float* __restrict__ Kg,
    const float* __restrict__ Vg, const float* __restrict__ taug,
    const float* __restrict__ dg, float* __restrict__ Og)
{
    __shared__ __align__(16) unsigned short Ks[2][64 * 64];
    __shared__ __align__(16) unsigned short Vt[2][64 * 64];

    const int tid  = threadIdx.x;
    const int w    = tid >> 6;
    const int lane = tid & 63;
    const int m    = lane & 15;
    const int quad = lane >> 4;

    const int bid = blockIdx.x;
    const int bh  = bid & (NBH - 1);
    const int g   = bid >> 5;
    const int tt  = (g < 8) ? (15 - g) : (g - 8);
    const int b   = bh >> 4;
    const int h   = bh & 15;

    const float qscale = taug[b] * (SCALE * LOG2E);
    const float dscale = SCALE * LOG2E;
    const int diag_st = 2 * tt + (w >> 2);
    const int thr = (w & 3) * 16 + m - quad * 4;

    bf16x8 qb[2];
    {
        const float* qp = Qg + ((size_t)(b * LL + tt * 128 + w * 16 + m) * HH + h) * EE + quad * 8;
        #pragma unroll
        for (int ch = 0; ch < 2; ++ch) {
            float4 f0 = *(const float4*)(qp + ch * 32);
            float4 f1 = *(const float4*)(qp + ch * 32 + 4);
            f0.x *= qscale; f0.y *= qscale; f0.z *= qscale; f0.w *= qscale;
            f1.x *= qscale; f1.y *= qscale; f1.z *= qscale; f1.w *= qscale;
            qb[ch] = __builtin_bit_cast(bf16x8, pack8(f0, f1));
        }
    }

    const int skey = tid >> 3, kc = tid & 7, se0 = (tid & 7) * 8;
    const int sv = (tid & 31) * 2, ve = (tid >> 5) * 4;
    const float* kbase = Kg + ((size_t)b * LL * HH + h) * EE;
    const float* vbase = Vg + ((size_t)b * LL * HH + h) * EE;
    const float* dbase = dg + b * LL;
    const int nst = 2 * tt + 2;

    float4 kr0, kr1, va, vb, dr0, dr1, dr2, dr3;
    {
        const float* kp = kbase + (size_t)skey * ROWSTR + se0;
        kr0 = ((const float4*)kp)[0]; kr1 = ((const float4*)kp)[1];
        const float* vp = vbase + (size_t)sv * ROWSTR + ve;
        va = *(const float4*)(vp); vb = *(const float4*)(vp + ROWSTR);
        const float* dp = dbase + quad * 4;
        dr0 = *(const float4*)(dp); dr1 = *(const float4*)(dp + 16);
        dr2 = *(const float4*)(dp + 32); dr3 = *(const float4*)(dp + 48);
    }

    f32x4 Oacc[4] = {};
    float l_ = 0.f;

    for (int st = 0; st < nst; ++st) {
        const int par = st & 1;
        unsigned short* KsP = Ks[par];
        unsigned short* VtP = Vt[par];

        *(uint4*)&KsP[skey * 64 + (kc ^ (skey & 7)) * 8] = pack8(kr0, kr1);
        {
            float ra[4] = {va.x, va.y, va.z, va.w};
            float rb[4] = {vb.x, vb.y, vb.z, vb.w};
            #pragma unroll
            for (int i = 0; i < 4; ++i) {
                const int e = ve + i;
                *(unsigned*)&VtP[e * 64 + (((sv >> 3) ^ (e & 7)) * 8) + (sv & 7)] = pkbf(ra[i], rb[i]);
            }
        }
        __syncthreads();

        f32x4 dvx[4];
        dvx[0] = f32x4{dr0.x * dscale, dr0.y * dscale, dr0.z * dscale, dr0.w * dscale};
        dvx[1] = f32x4{dr1.x * dscale, dr1.y * dscale, dr1.z * dscale, dr1.w * dscale};
        dvx[2] = f32x4{dr2.x * dscale, dr2.y * dscale, dr2.z * dscale, dr2.w * dscale};
        dvx[3] = f32x4{dr3.x * dscale, dr3.y * dscale, dr3.z * dscale, dr3.w * dscale};

        if (st + 1 < nst) {
            const int row = (st + 1) * 64;
            const float* kp = kbase + (size_t)(row + skey) * ROWSTR + se0;
            kr0 = ((const float4*)kp)[0]; kr1 = ((const float4*)kp)[1];
            const float* vp = vbase + (size_t)(row + sv) * ROWSTR + ve;
            va = *(const float4*)(vp); vb = *(const float4*)(vp + ROWSTR);
            const float* dp = dbase + row + quad * 4;
            dr0 = *(const float4*)(dp); dr1 = *(const float4*)(dp + 16);
            dr2 = *(const float4*)(dp + 32); dr3 = *(const float4*)(dp + 48);
        }

        if (st <= diag_st) {
            f32x4 S[4];
            #pragma unroll
            for (int n = 0; n < 4; ++n) {
                bf16x8 kf = *(const bf16x8*)&KsP[(16 * n + m) * 64 + (quad ^ (m & 7)) * 8];
                S[n] = __builtin_amdgcn_mfma_f32_16x16x32_bf16(kf, qb[0], dvx[n], 0, 0, 0);
            }
            #pragma unroll
            for (int n = 0; n < 4; ++n) {
                bf16x8 kf = *(const bf16x8*)&KsP[(16 * n + m) * 64 + ((quad + 4) ^ (m & 7)) * 8];
                S[n] = __builtin_amdgcn_mfma_f32_16x16x32_bf16(kf, qb[1], S[n], 0, 0, 0);
            }
            if (st == diag_st) {
                #pragma unroll
                for (int n = 0; n < 4; ++n)
                    #pragma unroll
                    for (int r = 0; r < 4; ++r)
                        if (16 * n + r > thr) S[n][r] = -INFINITY;
            }
            float rs[4];
            #pragma unroll
            for (int n = 0; n < 4; ++n) {
                float p0 = __builtin_amdgcn_exp2f(S[n][0]);
                float p1 = __builtin_amdgcn_exp2f(S[n][1]);
                float p2 = __builtin_amdgcn_exp2f(S[n][2]);
                float p3 = __builtin_amdgcn_exp2f(S[n][3]);
                S[n][0] = p0; S[n][1] = p1; S[n][2] = p2; S[n][3] = p3;
                rs[n] = (p0 + p1) + (p2 + p3);
            }
            l_ += (rs[0] + rs[1]) + (rs[2] + rs[3]);

            s16x4 pb[4];
            #pragma unroll
            for (int n = 0; n < 4; ++n) {
                uint2 u; u.x = pkbf(S[n][0], S[n][1]); u.y = pkbf(S[n][2], S[n][3]);
                pb[n] = __builtin_bit_cast(s16x4, u);
            }
            #pragma unroll
            for (int eb = 0; eb < 4; ++eb) {
                const int e = 16 * eb + m;
                s16x4 vf[4];
                #pragma unroll
                for (int n = 0; n < 4; ++n)
                    vf[n] = *(const s16x4*)&VtP[e * 64 + (((2 * n + (quad >> 1)) ^ (m & 7)) * 8) + (quad & 1) * 4];
                #pragma unroll
                for (int n = 0; n < 4; ++n)
                    Oacc[eb] = mfma16(vf[n], pb[n], Oacc[eb]);
            }
        }
    }

    {
        float lt = l_ + __shfl_xor(l_, 16);
        lt = lt + __shfl_xor(lt, 32);
        const float inv = __builtin_amdgcn_rcpf(lt);
        float* op = Og + ((size_t)(b * LL + tt * 128 + w * 16 + m) * HH + h) * EE + quad * 4;
        #pragma unroll
        for (int n = 0; n < 4; ++n) {
            float4 o = {Oacc[n][0] * inv, Oacc[n][1] * inv, Oacc[n][2] * inv, Oacc[n][3] * inv};
            *(float4*)(op + 16 * n) = o;
        }
    }
}

extern "C" void kernel_launch(void* const* d_in, const int* in_sizes, int n_in,
                              void* d_out, int out_size, void* d_ws, size_t ws_size,
                              hipStream_t stream) {
    const float* Q     = (const float*)d_in[0];
    const float* K     = (const float*)d_in[1];
    const float* V     = (const float*)d_in[2];
    const float* tau   = (const float*)d_in[3];
    const float* delta = (const float*)d_in[4];
    float* out = (float*)d_out;
    float* ws  = (float*)d_ws;
    if (ws_size >= WS_NEED) {
        dsprep<<<dim3(NBH * NST + 16), dim3(256), 0, stream>>>(K, V, delta, ws);
        dsattn_dma<<<dim3(NBH * NT), dim3(512), 0, stream>>>(Q, tau, ws, out);
    } else {
        dsattn_reg<<<dim3(NBH * NT), dim3(512), 0, stream>>>(Q, K, V, tau, delta, out);
    }
}

// Round 7
// 127.432 us; speedup vs baseline: 1.1143x; 1.0627x over previous
//
#include <hip/hip_runtime.h>
#include <math.h>

// Problem: B=2, L=2048, H=16, E=64. fp32 in/out.
#define LL 2048
#define HH 16
#define EE 64
#define ROWSTR (HH*EE)
#define NBH 32                  // B*H
#define NQT 32                  // 64-row q tiles per (b,h)
#define NST 32                  // 64-key tiles per (b,h)
#define SCALE 0.125f
#define LOG2E 1.4426950408889634f
#define TILE_SH 4096            // shorts per 64x64 bf16 tile image
// ws layout: [4096 floats dscaled][Kpre bf16 images][Vpre bf16 images]
#define KPRE_OFF 4096                                   // in floats
#define TILES_TOTAL ((size_t)NBH * NST)
#define WS_NEED (16384ull + 2ull * TILES_TOTAL * TILE_SH * 2ull)

using bf16x8 = __attribute__((ext_vector_type(8))) __bf16;
using f32x4  = __attribute__((ext_vector_type(4))) float;
using s16x4  = __attribute__((ext_vector_type(4))) short;

// fast fp32->bf16 (round-half-up) pair pack: 2 adds + 1 v_perm
__device__ __forceinline__ unsigned pkbf(float lo, float hi) {
    unsigned l = __builtin_bit_cast(unsigned, lo) + 0x8000u;
    unsigned h = __builtin_bit_cast(unsigned, hi) + 0x8000u;
    return __builtin_amdgcn_perm(h, l, 0x07060302u);
}
__device__ __forceinline__ uint4 pack8(float4 a, float4 b) {
    uint4 u; u.x = pkbf(a.x, a.y); u.y = pkbf(a.z, a.w);
    u.z = pkbf(b.x, b.y); u.w = pkbf(b.z, b.w); return u;
}

#if __has_builtin(__builtin_amdgcn_mfma_f32_16x16x16_bf16)
using bf16x4 = __attribute__((ext_vector_type(4))) __bf16;
__device__ __forceinline__ f32x4 mfma16(s16x4 a, s16x4 b, f32x4 c) {
    return __builtin_amdgcn_mfma_f32_16x16x16_bf16(
        __builtin_bit_cast(bf16x4, a), __builtin_bit_cast(bf16x4, b), c, 0, 0, 0);
}
#else
__device__ __forceinline__ f32x4 mfma16(s16x4 a, s16x4 b, f32x4 c) {
    return __builtin_amdgcn_mfma_f32_16x16x16bf16_1k(a, b, c, 0, 0, 0);
}
#endif

// async 16B global->LDS (LDS dest is wave-uniform base + lane*16)
__device__ __forceinline__ void gl_lds16(const void* g, void* l) {
    __builtin_amdgcn_global_load_lds(
        (const __attribute__((address_space(1))) unsigned int*)(unsigned long long)g,
        (__attribute__((address_space(3))) unsigned int*)(unsigned long long)l,
        16, 0, 0);
}

// ---------------- prep: K/V -> bf16 DMA-ready tile images + delta prescale ----
// K image: row k (natural), 8 chunks of 8 shorts, chunk c at position c^(k&7).
// V image: row e, column sigma(s) = (s&3) + ((s>>4)&3)*4 + ((s>>2)&3)*16,
//          chunk c at position c^(e&7).  (sigma makes PV A-frags contiguous b128)
__global__ __launch_bounds__(256) void dsprep(
    const float* __restrict__ K, const float* __restrict__ V,
    const float* __restrict__ delta, float* __restrict__ ws)
{
    const int bid = blockIdx.x;
    const int t = threadIdx.x;
    float* dsc = ws;
    unsigned short* kpre = (unsigned short*)(ws + KPRE_OFF);
    unsigned short* vpre = kpre + TILES_TOTAL * TILE_SH;

    if (bid >= NBH * NST) {               // delta prescale: 16 trailing blocks
        const int i = (bid - NBH * NST) * 256 + t;
        dsc[i] = delta[i] * (SCALE * LOG2E);
        return;
    }
    const int bh = bid & 31, st = bid >> 5;
    const int b = bh >> 4, h = bh & 15;

    // ---- K tile ----
    unsigned short* kimg = kpre + ((size_t)bh * NST + st) * TILE_SH;
    #pragma unroll
    for (int i = 0; i < 2; ++i) {
        const int slot = t + i * 256;     // 0..511: (k, chunk)
        const int k = slot >> 3, c = slot & 7;
        const float* src = K + ((size_t)(b * LL + st * 64 + k) * HH + h) * EE + c * 8;
        float4 a = ((const float4*)src)[0], bq = ((const float4*)src)[1];
        *(uint4*)&kimg[k * 64 + (c ^ (k & 7)) * 8] = pack8(a, bq);
    }

    // ---- V tile: coalesced read -> LDS fp32 (padded) -> transposed bf16 image ----
    __shared__ float vt[64 * 65];
    {
        const int s = t >> 2, seg = (t & 3) * 16;
        const float* src = V + ((size_t)(b * LL + st * 64 + s) * HH + h) * EE + seg;
        #pragma unroll
        for (int i = 0; i < 4; ++i) {
            float4 f = ((const float4*)src)[i];
            vt[s * 65 + seg + 4 * i + 0] = f.x;
            vt[s * 65 + seg + 4 * i + 1] = f.y;
            vt[s * 65 + seg + 4 * i + 2] = f.z;
            vt[s * 65 + seg + 4 * i + 3] = f.w;
        }
    }
    __syncthreads();
    {
        unsigned short* vimg = vpre + ((size_t)bh * NST + st) * TILE_SH;
        const int e = t >> 2, g = t & 3;  // sigma range [16g, 16g+16)
        unsigned u[8];
        #pragma unroll
        for (int A = 0; A < 4; ++A) {     // sigma = 16g + 4A + C  <->  s = 16A + 4g + C
            float x0 = vt[(16 * A + 4 * g + 0) * 65 + e];
            float x1 = vt[(16 * A + 4 * g + 1) * 65 + e];
            float x2 = vt[(16 * A + 4 * g + 2) * 65 + e];
            float x3 = vt[(16 * A + 4 * g + 3) * 65 + e];
            u[2 * A]     = pkbf(x0, x1);
            u[2 * A + 1] = pkbf(x2, x3);
        }
        *(uint4*)&vimg[e * 64 + ((2 * g)     ^ (e & 7)) * 8] = uint4{u[0], u[1], u[2], u[3]};
        *(uint4*)&vimg[e * 64 + ((2 * g + 1) ^ (e & 7)) * 8] = uint4{u[4], u[5], u[6], u[7]};
    }
}

// ---------------- main: DMA-staged flash attention ----------------
// WG = 256 thr = 4 waves; one (b,h,64-row q tile) per block -> 1024 blocks
// (fine-grained for residency/balance). Fixed-reference softmax (p = exp2(S),
// logits bounded). K/V tiles arrive via global_load_lds (async, zero staging
// VALU), double-buffered, one barrier per key tile.
__global__ __launch_bounds__(256, 8) void dsattn_dma(
    const float* __restrict__ Qg, const float* __restrict__ taug,
    const float* __restrict__ ws_, float* __restrict__ Og)
{
    __shared__ __align__(16) unsigned short Ks[2][TILE_SH];
    __shared__ __align__(16) unsigned short Vt[2][TILE_SH];

    const int tid  = threadIdx.x;
    const int w    = tid >> 6;       // wave 0..3
    const int lane = tid & 63;
    const int m    = lane & 15;
    const int quad = lane >> 4;

    const int bid = blockIdx.x;
    const int bh  = bid & (NBH - 1);
    const int qt  = (NQT - 1) - (bid >> 5);   // longest blocks dispatch first
    const int b   = bh >> 4;
    const int h   = bh & 15;

    const float* dsc = ws_;
    const unsigned short* kpre = (const unsigned short*)(ws_ + KPRE_OFF);
    const unsigned short* vpre = kpre + TILES_TOTAL * TILE_SH;
    const unsigned short* ktiles = kpre + (size_t)bh * NST * TILE_SH;
    const unsigned short* vtiles = vpre + (size_t)bh * NST * TILE_SH;

    const float qscale = taug[b] * (SCALE * LOG2E);
    const int thr = w * 16 + m - quad * 4;    // mask when 16n + r > thr at diag

    // ---- Q fragment (B-operand: B[k=e][col=q=m]) with tau*scale*log2e folded ----
    bf16x8 qb[2];
    {
        const float* qp = Qg + ((size_t)(b * LL + qt * 64 + w * 16 + m) * HH + h) * EE + quad * 8;
        #pragma unroll
        for (int ch = 0; ch < 2; ++ch) {
            float4 f0 = *(const float4*)(qp + ch * 32);
            float4 f1 = *(const float4*)(qp + ch * 32 + 4);
            f0.x *= qscale; f0.y *= qscale; f0.z *= qscale; f0.w *= qscale;
            f1.x *= qscale; f1.y *= qscale; f1.z *= qscale; f1.w *= qscale;
            qb[ch] = __builtin_bit_cast(bf16x8, pack8(f0, f1));
        }
    }

    const float* dbase = dsc + b * LL + quad * 4;

    // prologue DMA: tile 0 -> buffer 0 (each thread moves 2x16B of K and V)
    gl_lds16(ktiles + tid * 8,        &Ks[0][w * 512]);
    gl_lds16(ktiles + 2048 + tid * 8, &Ks[0][2048 + w * 512]);
    gl_lds16(vtiles + tid * 8,        &Vt[0][w * 512]);
    gl_lds16(vtiles + 2048 + tid * 8, &Vt[0][2048 + w * 512]);

    f32x4 Oacc[4] = {};
    float l_ = 0.f;

    for (int st = 0; st <= qt; ++st) {
        const int par = st & 1;
        const unsigned short* KsP = Ks[par];
        const unsigned short* VtP = Vt[par];

        __syncthreads();   // drains this tile's DMA + prior reads of other buffer

        // async prefetch next tile into the other buffer (overlaps compute)
        if (st < qt) {
            const unsigned short* kn = ktiles + (st + 1) * TILE_SH;
            const unsigned short* vn = vtiles + (st + 1) * TILE_SH;
            gl_lds16(kn + tid * 8,        &Ks[par ^ 1][w * 512]);
            gl_lds16(kn + 2048 + tid * 8, &Ks[par ^ 1][2048 + w * 512]);
            gl_lds16(vn + tid * 8,        &Vt[par ^ 1][w * 512]);
            gl_lds16(vn + 2048 + tid * 8, &Vt[par ^ 1][2048 + w * 512]);
        }

        // delta for this tile (prescaled, fp32-exact C-init)
        const float* dp = dbase + st * 64;
        f32x4 S[4];
        S[0] = __builtin_bit_cast(f32x4, *(const float4*)(dp));
        S[1] = __builtin_bit_cast(f32x4, *(const float4*)(dp + 16));
        S[2] = __builtin_bit_cast(f32x4, *(const float4*)(dp + 32));
        S[3] = __builtin_bit_cast(f32x4, *(const float4*)(dp + 48));

        // ---- S^T = K·Q^T + delta  (D rows=keys, cols=q), log2 units ----
        #pragma unroll
        for (int n = 0; n < 4; ++n) {
            bf16x8 kf = *(const bf16x8*)&KsP[(16 * n + m) * 64 + (quad ^ (m & 7)) * 8];
            S[n] = __builtin_amdgcn_mfma_f32_16x16x32_bf16(kf, qb[0], S[n], 0, 0, 0);
        }
        #pragma unroll
        for (int n = 0; n < 4; ++n) {
            bf16x8 kf = *(const bf16x8*)&KsP[(16 * n + m) * 64 + ((quad + 4) ^ (m & 7)) * 8];
            S[n] = __builtin_amdgcn_mfma_f32_16x16x32_bf16(kf, qb[1], S[n], 0, 0, 0);
        }

        if (st == qt) {   // causal mask, diagonal tile only
            #pragma unroll
            for (int n = 0; n < 4; ++n)
                #pragma unroll
                for (int r = 0; r < 4; ++r)
                    if (16 * n + r > thr) S[n][r] = -INFINITY;
        }

        // ---- fixed-ref softmax: p = exp2(S) ----
        float rs[4];
        #pragma unroll
        for (int n = 0; n < 4; ++n) {
            float p0 = __builtin_amdgcn_exp2f(S[n][0]);
            float p1 = __builtin_amdgcn_exp2f(S[n][1]);
            float p2 = __builtin_amdgcn_exp2f(S[n][2]);
            float p3 = __builtin_amdgcn_exp2f(S[n][3]);
            S[n][0] = p0; S[n][1] = p1; S[n][2] = p2; S[n][3] = p3;
            rs[n] = (p0 + p1) + (p2 + p3);
        }
        l_ += (rs[0] + rs[1]) + (rs[2] + rs[3]);

        // ---- pack P as K=16 B-frags (register-direct) ----
        s16x4 pb[4];
        #pragma unroll
        for (int n = 0; n < 4; ++n) {
            uint2 u; u.x = pkbf(S[n][0], S[n][1]); u.y = pkbf(S[n][2], S[n][3]);
            pb[n] = __builtin_bit_cast(s16x4, u);
        }

        // ---- O^T += V^T·P^T; sigma layout -> 2 contiguous b128 per eb ----
        #pragma unroll
        for (int eb = 0; eb < 4; ++eb) {
            const int e = 16 * eb + m;
            uint4 r0 = *(const uint4*)&VtP[e * 64 + ((2 * quad)     ^ (m & 7)) * 8];
            uint4 r1 = *(const uint4*)&VtP[e * 64 + ((2 * quad + 1) ^ (m & 7)) * 8];
            f32x4 o = Oacc[eb];
            o = mfma16(__builtin_bit_cast(s16x4, uint2{r0.x, r0.y}), pb[0], o);
            o = mfma16(__builtin_bit_cast(s16x4, uint2{r0.z, r0.w}), pb[1], o);
            o = mfma16(__builtin_bit_cast(s16x4, uint2{r1.x, r1.y}), pb[2], o);
            o = mfma16(__builtin_bit_cast(s16x4, uint2{r1.z, r1.w}), pb[3], o);
            Oacc[eb] = o;
        }
    }

    // ---- epilogue: reduce l across quads, normalize, float4 stores ----
    {
        float lt = l_ + __shfl_xor(l_, 16);
        lt = lt + __shfl_xor(lt, 32);
        const float inv = __builtin_amdgcn_rcpf(lt);
        float* op = Og + ((size_t)(b * LL + qt * 64 + w * 16 + m) * HH + h) * EE + quad * 4;
        #pragma unroll
        for (int n = 0; n < 4; ++n) {
            float4 o = {Oacc[n][0] * inv, Oacc[n][1] * inv, Oacc[n][2] * inv, Oacc[n][3] * inv};
            *(float4*)(op + 16 * n) = o;
        }
    }
}

// ---------------- fallback (register-staging path, no workspace) ----------
__global__ __launch_bounds__(512, 4) void dsattn_reg(
    const float* __restrict__ Qg, const float* __restrict__ Kg,
    const float* __restrict__ Vg, const float* __restrict__ taug,
    const float* __restrict__ dg, float* __restrict__ Og)
{
    __shared__ __align__(16) unsigned short Ks[2][64 * 64];
    __shared__ __align__(16) unsigned short Vt[2][64 * 64];

    const int tid  = threadIdx.x;
    const int w    = tid >> 6;
    const int lane = tid & 63;
    const int m    = lane & 15;
    const int quad = lane >> 4;

    const int bid = blockIdx.x;
    const int bh  = bid & (NBH - 1);
    const int g   = bid >> 5;
    const int tt  = (g < 8) ? (15 - g) : (g - 8);
    const int b   = bh >> 4;
    const int h   = bh & 15;

    const float qscale = taug[b] * (SCALE * LOG2E);
    const float dscale = SCALE * LOG2E;
    const int diag_st = 2 * tt + (w >> 2);
    const int thr = (w & 3) * 16 + m - quad * 4;

    bf16x8 qb[2];
    {
        const float* qp = Qg + ((size_t)(b * LL + tt * 128 + w * 16 + m) * HH + h) * EE + quad * 8;
        #pragma unroll
        for (int ch = 0; ch < 2; ++ch) {
            float4 f0 = *(const float4*)(qp + ch * 32);
            float4 f1 = *(const float4*)(qp + ch * 32 + 4);
            f0.x *= qscale; f0.y *= qscale; f0.z *= qscale; f0.w *= qscale;
            f1.x *= qscale; f1.y *= qscale; f1.z *= qscale; f1.w *= qscale;
            qb[ch] = __builtin_bit_cast(bf16x8, pack8(f0, f1));
        }
    }

    const int skey = tid >> 3, kc = tid & 7, se0 = (tid & 7) * 8;
    const int sv = (tid & 31) * 2, ve = (tid >> 5) * 4;
    const float* kbase = Kg + ((size_t)b * LL * HH + h) * EE;
    const float* vbase = Vg + ((size_t)b * LL * HH + h) * EE;
    const float* dbase = dg + b * LL;
    const int nst = 2 * tt + 2;

    float4 kr0, kr1, va, vb, dr0, dr1, dr2, dr3;
    {
        const float* kp = kbase + (size_t)skey * ROWSTR + se0;
        kr0 = ((const float4*)kp)[0]; kr1 = ((const float4*)kp)[1];
        const float* vp = vbase + (size_t)sv * ROWSTR + ve;
        va = *(const float4*)(vp); vb = *(const float4*)(vp + ROWSTR);
        const float* dp = dbase + quad * 4;
        dr0 = *(const float4*)(dp); dr1 = *(const float4*)(dp + 16);
        dr2 = *(const float4*)(dp + 32); dr3 = *(const float4*)(dp + 48);
    }

    f32x4 Oacc[4] = {};
    float l_ = 0.f;

    for (int st = 0; st < nst; ++st) {
        const int par = st & 1;
        unsigned short* KsP = Ks[par];
        unsigned short* VtP = Vt[par];

        *(uint4*)&KsP[skey * 64 + (kc ^ (skey & 7)) * 8] = pack8(kr0, kr1);
        {
            float ra[4] = {va.x, va.y, va.z, va.w};
            float rb[4] = {vb.x, vb.y, vb.z, vb.w};
            #pragma unroll
            for (int i = 0; i < 4; ++i) {
                const int e = ve + i;
                *(unsigned*)&VtP[e * 64 + (((sv >> 3) ^ (e & 7)) * 8) + (sv & 7)] = pkbf(ra[i], rb[i]);
            }
        }
        __syncthreads();

        f32x4 dvx[4];
        dvx[0] = f32x4{dr0.x * dscale, dr0.y * dscale, dr0.z * dscale, dr0.w * dscale};
        dvx[1] = f32x4{dr1.x * dscale, dr1.y * dscale, dr1.z * dscale, dr1.w * dscale};
        dvx[2] = f32x4{dr2.x * dscale, dr2.y * dscale, dr2.z * dscale, dr2.w * dscale};
        dvx[3] = f32x4{dr3.x * dscale, dr3.y * dscale, dr3.z * dscale, dr3.w * dscale};

        if (st + 1 < nst) {
            const int row = (st + 1) * 64;
            const float* kp = kbase + (size_t)(row + skey) * ROWSTR + se0;
            kr0 = ((const float4*)kp)[0]; kr1 = ((const float4*)kp)[1];
            const float* vp = vbase + (size_t)(row + sv) * ROWSTR + ve;
            va = *(const float4*)(vp); vb = *(const float4*)(vp + ROWSTR);
            const float* dp = dbase + row + quad * 4;
            dr0 = *(const float4*)(dp); dr1 = *(const float4*)(dp + 16);
            dr2 = *(const float4*)(dp + 32); dr3 = *(const float4*)(dp + 48);
        }

        if (st <= diag_st) {
            f32x4 S[4];
            #pragma unroll
            for (int n = 0; n < 4; ++n) {
                bf16x8 kf = *(const bf16x8*)&KsP[(16 * n + m) * 64 + (quad ^ (m & 7)) * 8];
                S[n] = __builtin_amdgcn_mfma_f32_16x16x32_bf16(kf, qb[0], dvx[n], 0, 0, 0);
            }
            #pragma unroll
            for (int n = 0; n < 4; ++n) {
                bf16x8 kf = *(const bf16x8*)&KsP[(16 * n + m) * 64 + ((quad + 4) ^ (m & 7)) * 8];
                S[n] = __builtin_amdgcn_mfma_f32_16x16x32_bf16(kf, qb[1], S[n], 0, 0, 0);
            }
            if (st == diag_st) {
                #pragma unroll
                for (int n = 0; n < 4; ++n)
                    #pragma unroll
                    for (int r = 0; r < 4; ++r)
                        if (16 * n + r > thr) S[n][r] = -INFINITY;
            }
            float rs[4];
            #pragma unroll
            for (int n = 0; n < 4; ++n) {
                float p0 = __builtin_amdgcn_exp2f(S[n][0]);
                float p1 = __builtin_amdgcn_exp2f(S[n][1]);
                float p2 = __builtin_amdgcn_exp2f(S[n][2]);
                float p3 = __builtin_amdgcn_exp2f(S[n][3]);
                S[n][0] = p0; S[n][1] = p1; S[n][2] = p2; S[n][3] = p3;
                rs[n] = (p0 + p1) + (p2 + p3);
            }
            l_ += (rs[0] + rs[1]) + (rs[2] + rs[3]);

            s16x4 pb[4];
            #pragma unroll
            for (int n = 0; n < 4; ++n) {
                uint2 u; u.x = pkbf(S[n][0], S[n][1]); u.y = pkbf(S[n][2], S[n][3]);
                pb[n] = __builtin_bit_cast(s16x4, u);
            }
            #pragma unroll
            for (int eb = 0; eb < 4; ++eb) {
                const int e = 16 * eb + m;
                s16x4 vf[4];
                #pragma unroll
                for (int n = 0; n < 4; ++n)
                    vf[n] = *(const s16x4*)&VtP[e * 64 + (((2 * n + (quad >> 1)) ^ (m & 7)) * 8) + (quad & 1) * 4];
                #pragma unroll
                for (int n = 0; n < 4; ++n)
                    Oacc[eb] = mfma16(vf[n], pb[n], Oacc[eb]);
            }
        }
    }

    {
        float lt = l_ + __shfl_xor(l_, 16);
        lt = lt + __shfl_xor(lt, 32);
        const float inv = __builtin_amdgcn_rcpf(lt);
        float* op = Og + ((size_t)(b * LL + tt * 128 + w * 16 + m) * HH + h) * EE + quad * 4;
        #pragma unroll
        for (int n = 0; n < 4; ++n) {
            float4 o = {Oacc[n][0] * inv, Oacc[n][1] * inv, Oacc[n][2] * inv, Oacc[n][3] * inv};
            *(float4*)(op + 16 * n) = o;
        }
    }
}

extern "C" void kernel_launch(void* const* d_in, const int* in_sizes, int n_in,
                              void* d_out, int out_size, void* d_ws, size_t ws_size,
                              hipStream_t stream) {
    const float* Q     = (const float*)d_in[0];
    const float* K     = (const float*)d_in[1];
    const float* V     = (const float*)d_in[2];
    const float* tau   = (const float*)d_in[3];
    const float* delta = (const float*)d_in[4];
    float* out = (float*)d_out;
    float* ws  = (float*)d_ws;
    if (ws_size >= WS_NEED) {
        dsprep<<<dim3(NBH * NST + 16), dim3(256), 0, stream>>>(K, V, delta, ws);
        dsattn_dma<<<dim3(NBH * NQT), dim3(256), 0, stream>>>(Q, tau, ws, out);
    } else {
        dsattn_reg<<<dim3(NBH * (NQT / 2)), dim3(512), 0, stream>>>(Q, K, V, tau, delta, out);
    }
}